// Round 9
// baseline (498.447 us; speedup 1.0000x reference)
//
#include <hip/hip_runtime.h>
#include <hip/hip_bf16.h>

// MemoryGraph: B=8, NC=256, Nc=128, D_n=64, HS=256, HM=128, ALPHA=2
// R9: barrier-free row-streaming decomposition.
//   cvt_w   : weights -> bf16 (w1m/w2m/w1s as swizzled LDS images, w2s linear)
//   inj_k   : inj = x @ injw^T + injb          (4 threads/output, coalesced)
//   msg_k   : per 16-row group: h_id -> m      (grid-stride, 0 barriers in loop)
//   agg_k   : agg = W @ m (mT from global)     (no LDS, no barriers)
//   state_k : [h_id|agg] -> dh -> h_new/decay  (grid-stride, 0 barriers in loop)
//   hebb_k  : outer + hebbian/W_new            (unchanged, HBM roofline)
// Scratch in out_hb region (written last by hebb): inj 1MB, mT bf16 33MB.

#define NCELL 256

typedef __attribute__((ext_vector_type(8))) short bf16x8;
typedef __attribute__((ext_vector_type(4))) float f32x4;
typedef __attribute__((ext_vector_type(4))) unsigned short u16x4;

#define MFMA(a, b, c) __builtin_amdgcn_mfma_f32_16x16x32_bf16((a), (b), (c), 0, 0, 0)

__device__ __forceinline__ unsigned short f2bf(float f) {
    return __builtin_bit_cast(unsigned short, __float2bfloat16(f));
}
__device__ __forceinline__ float frcp(float x) { return __builtin_amdgcn_rcpf(x); }
__device__ __forceinline__ float sigm(float v) { return frcp(1.0f + __expf(-v)); }
__device__ __forceinline__ float ftanh(float x) {
    float e = __expf(2.0f * x);
    return 1.0f - 2.0f * frcp(e + 1.0f);
}

// 16B-granule XOR swizzle within a row.
__device__ __forceinline__ int swzg(int col, int row) {
    return (((col >> 3) ^ (row & 7)) << 3) | (col & 7);
}
// per-wave [16][32] stage buffer swizzle
__device__ __forceinline__ int swb(int row, int col) {
    return row * 32 + ((((col >> 3) ^ row) & 3) << 3) + (col & 7);
}
__device__ __forceinline__ int sw64(int row, int col) {
    return row * 64 + ((((col >> 3) ^ row) & 7) << 3) + (col & 7);
}

// ws layout (ushort): [0,8192) w1m img [128][64]; [8192,16384) w2m img [64][128];
// [16384,49152) w1s img [256][128]; [49152,65536) w2s LINEAR [64][256].
__global__ void cvt_w(const float* __restrict__ a, const float* __restrict__ b,
                      const float* __restrict__ c, const float* __restrict__ d,
                      unsigned short* __restrict__ dst) {
    int i = blockIdx.x * 256 + threadIdx.x;   // 65536 total
    if (i < 8192) {
        int row = i >> 6, col = i & 63;
        dst[row * 64 + swzg(col, row)] = f2bf(a[i]);
    } else if (i < 16384) {
        int j = i - 8192;
        int row = j >> 7, col = j & 127;
        dst[8192 + row * 128 + swzg(col, row)] = f2bf(b[j]);
    } else if (i < 49152) {
        int j = i - 16384;
        int row = j >> 7, col = j & 127;
        dst[16384 + row * 128 + swzg(col, row)] = f2bf(c[j]);
    } else {
        dst[i] = f2bf(d[i - 49152]);
    }
}

// ================= inj = x @ injw^T + injb =================
__global__ __launch_bounds__(256, 8)
void inj_kernel(const float* __restrict__ x, const float* __restrict__ injw,
                const float* __restrict__ injb, float* __restrict__ inj_ws) {
    int t = blockIdx.x * 256 + threadIdx.x;   // 1048576 = 262144 outputs x 4
    int oid = t >> 2;
    int part = t & 3;
    int cell = oid >> 7, o = oid & 127, c = cell & (NCELL - 1);
    const float4* wr = (const float4*)(injw + (c * 128 + o) * 64 + part * 16);
    const float4* xr = (const float4*)(x + cell * 64 + part * 16);
    float s = 0.f;
    #pragma unroll
    for (int i = 0; i < 4; ++i) {
        float4 a = wr[i], b = xr[i];
        s += a.x * b.x + a.y * b.y + a.z * b.z + a.w * b.w;
    }
    s += __shfl_xor(s, 1);
    s += __shfl_xor(s, 2);
    if (part == 0) inj_ws[oid] = s + injb[c * 128 + o];
}

// ================= msg MLP, row-streaming =================
__global__ __launch_bounds__(256, 4)
void msg_kernel(const float* __restrict__ h, const float* __restrict__ nid,
                const float* __restrict__ mb1, const float* __restrict__ mb2,
                const unsigned short* __restrict__ wbf,
                const float* __restrict__ inj_ws,
                float* __restrict__ out_m, unsigned short* __restrict__ mT_g) {
    const int tid = threadIdx.x;
    const int wv = tid >> 6;
    const int lane = tid & 63;
    const int lr = lane & 15;
    const int lg = lane >> 4;

    __shared__ alignas(16) unsigned short w1m_s[8192];   // 16K img
    __shared__ alignas(16) unsigned short w2m_s[8192];   // 16K img
    __shared__ alignas(16) unsigned short hbuf_all[2048]; // 4K
    unsigned short* hbuf = hbuf_all + wv * 512;

    {   // stage weights (linear copy of pre-swizzled images)
        const uint4* s1 = (const uint4*)wbf;
        const uint4* s2 = (const uint4*)(wbf + 8192);
        uint4* d1 = (uint4*)w1m_s;
        uint4* d2 = (uint4*)w2m_s;
        #pragma unroll
        for (int i = 0; i < 4; ++i) { d1[tid + i * 256] = s1[tid + i * 256]; }
        #pragma unroll
        for (int i = 0; i < 4; ++i) { d2[tid + i * 256] = s2[tid + i * 256]; }
    }
    __syncthreads();

    // loop-invariant biases
    float mb1v[8], mb2v[4];
    #pragma unroll
    for (int ch = 0; ch < 4; ++ch)
        #pragma unroll
        for (int ht = 0; ht < 2; ++ht)
            mb1v[ch * 2 + ht] = mb1[ch * 32 + ht * 16 + lr];
    #pragma unroll
    for (int dt = 0; dt < 4; ++dt) mb2v[dt] = mb2[dt * 16 + lr];

    const int g0 = blockIdx.x * 16 + wv * 4;
    for (int g = g0; g < g0 + 4; ++g) {          // 16384 groups of 16 rows
        const int row0 = g * 16;
        const int cell = row0 >> 7;
        const int arow = row0 + lr;
        const int nro = arow & 127;

        bf16x8 aH[2];
        #pragma unroll
        for (int ks = 0; ks < 2; ++ks) {
            const float* hr = h + (size_t)arow * 64 + ks * 32 + lg * 8;
            const float* nr = nid + (size_t)(arow & 32767) * 64 + ks * 32 + lg * 8;
            float4 a0 = *(const float4*)hr;
            float4 a1 = *(const float4*)(hr + 4);
            float4 n0 = *(const float4*)nr;
            float4 n1 = *(const float4*)(nr + 4);
            float v[8] = {a0.x, a0.y, a0.z, a0.w, a1.x, a1.y, a1.z, a1.w};
            float nn[8] = {n0.x, n0.y, n0.z, n0.w, n1.x, n1.y, n1.z, n1.w};
            unsigned short us[8];
            #pragma unroll
            for (int j = 0; j < 8; ++j) {
                float hv = v[j] + nn[j];
                if (nro < 2) hv += inj_ws[cell * 128 + nro * 64 + ks * 32 + lg * 8 + j];
                us[j] = f2bf(hv);
            }
            aH[ks] = *(bf16x8*)us;
        }

        f32x4 accM[4];
        #pragma unroll
        for (int dt = 0; dt < 4; ++dt) accM[dt] = (f32x4){0.f, 0.f, 0.f, 0.f};
        #pragma unroll
        for (int ch = 0; ch < 4; ++ch) {
            f32x4 accH[2];
            accH[0] = (f32x4){0.f, 0.f, 0.f, 0.f};
            accH[1] = (f32x4){0.f, 0.f, 0.f, 0.f};
            #pragma unroll
            for (int ks = 0; ks < 2; ++ks)
                #pragma unroll
                for (int ht = 0; ht < 2; ++ht) {
                    const int wrow = ch * 32 + ht * 16 + lr;
                    bf16x8 bw = *(const bf16x8*)&w1m_s[wrow * 64 + swzg(ks * 32 + lg * 8, wrow)];
                    accH[ht] = MFMA(aH[ks], bw, accH[ht]);
                }
            #pragma unroll
            for (int ht = 0; ht < 2; ++ht)
                #pragma unroll
                for (int r = 0; r < 4; ++r)
                    hbuf[swb(lg * 4 + r, ht * 16 + lr)] =
                        f2bf(ftanh(accH[ht][r] + mb1v[ch * 2 + ht]));
            bf16x8 aM = *(const bf16x8*)&hbuf[swb(lr, lg * 8)];
            #pragma unroll
            for (int dt = 0; dt < 4; ++dt) {
                const int wrow = dt * 16 + lr;
                bf16x8 bw = *(const bf16x8*)&w2m_s[wrow * 128 + swzg(ch * 32 + lg * 8, wrow)];
                accM[dt] = MFMA(aM, bw, accM[dt]);
            }
        }

        // epilogue: m f32 (output) + mT bf16 (scratch, C-fragment-local pack)
        const int nrow0 = (row0 & 127) + lg * 4;
        #pragma unroll
        for (int dt = 0; dt < 4; ++dt) {
            unsigned short um[4];
            #pragma unroll
            for (int r = 0; r < 4; ++r) {
                float mv = accM[dt][r] + mb2v[dt];
                out_m[(size_t)(row0 + lg * 4 + r) * 64 + dt * 16 + lr] = mv;
                um[r] = f2bf(mv);
            }
            *(u16x4*)&mT_g[(size_t)cell * 8192 + (dt * 16 + lr) * 128 + nrow0] =
                *(u16x4*)um;
        }
    }
}

// ================= agg = W @ m (no LDS, no barriers) =================
__global__ __launch_bounds__(256, 6)
void agg_kernel(const float* __restrict__ W, const unsigned short* __restrict__ mT_g,
                float* __restrict__ agg_ws) {
    const int cell = blockIdx.x;
    const int tid = threadIdx.x;
    const int wv = tid >> 6;
    const int lane = tid & 63;
    const int lr = lane & 15;
    const int lg = lane >> 4;

    const unsigned short* mTc = mT_g + (size_t)cell * 8192;
    const float* Wbase = W + (size_t)cell * 16384;

    f32x4 accA[2][4];
    #pragma unroll
    for (int rt = 0; rt < 2; ++rt)
        #pragma unroll
        for (int dt = 0; dt < 4; ++dt)
            accA[rt][dt] = (f32x4){0.f, 0.f, 0.f, 0.f};

    #pragma unroll
    for (int ks = 0; ks < 4; ++ks) {
        bf16x8 bmv[4];
        #pragma unroll
        for (int dt = 0; dt < 4; ++dt)
            bmv[dt] = *(const bf16x8*)&mTc[(dt * 16 + lr) * 128 + ks * 32 + lg * 8];
        #pragma unroll
        for (int rt = 0; rt < 2; ++rt) {
            const float* wr = Wbase + (wv * 32 + rt * 16 + lr) * 128 + ks * 32 + lg * 8;
            float4 wa = *(const float4*)wr;
            float4 wb = *(const float4*)(wr + 4);
            unsigned short uw[8] = {f2bf(wa.x), f2bf(wa.y), f2bf(wa.z), f2bf(wa.w),
                                    f2bf(wb.x), f2bf(wb.y), f2bf(wb.z), f2bf(wb.w)};
            bf16x8 aW = *(bf16x8*)uw;
            #pragma unroll
            for (int dt = 0; dt < 4; ++dt)
                accA[rt][dt] = MFMA(aW, bmv[dt], accA[rt][dt]);
        }
    }
    float* adst = agg_ws + (size_t)cell * 8192;
    #pragma unroll
    for (int rt = 0; rt < 2; ++rt)
        #pragma unroll
        for (int dt = 0; dt < 4; ++dt)
            #pragma unroll
            for (int r = 0; r < 4; ++r)
                adst[(wv * 32 + rt * 16 + lg * 4 + r) * 64 + dt * 16 + lr] = accA[rt][dt][r];
}

// ================= state MLP + h_new/decay, row-streaming =================
__global__ __launch_bounds__(512, 4)
void state_kernel(const float* __restrict__ h, const float* __restrict__ nid,
                  const float* __restrict__ decay,
                  const float* __restrict__ sb1, const float* __restrict__ sb2,
                  const float* __restrict__ dgl,
                  const unsigned short* __restrict__ wbf,
                  const float* __restrict__ inj_ws, const float* __restrict__ agg_ws,
                  float* __restrict__ out_h, float* __restrict__ out_d) {
    const int tid = threadIdx.x;
    const int wv = tid >> 6;                 // 8 waves
    const int lane = tid & 63;
    const int lr = lane & 15;
    const int lg = lane >> 4;

    __shared__ alignas(16) unsigned short w1s_s[32768];   // 64K img
    __shared__ alignas(16) unsigned short hbuf_all[4096]; // 8K
    unsigned short* hbuf = hbuf_all + wv * 512;

    {   // stage w1s image (linear copy)
        const uint4* s1 = (const uint4*)(wbf + 16384);
        uint4* d1 = (uint4*)w1s_s;
        #pragma unroll
        for (int i = 0; i < 8; ++i) d1[tid + i * 512] = s1[tid + i * 512];
    }
    __syncthreads();

    const unsigned short* w2s_g = wbf + 49152;   // linear [64][256]

    float sb1v[16], sb2v[4];
    #pragma unroll
    for (int ch = 0; ch < 8; ++ch)
        #pragma unroll
        for (int ht = 0; ht < 2; ++ht)
            sb1v[ch * 2 + ht] = sb1[ch * 32 + ht * 16 + lr];
    #pragma unroll
    for (int dt = 0; dt < 4; ++dt) sb2v[dt] = sb2[dt * 16 + lr];

    const int g0 = blockIdx.x * 16 + wv * 2;
    for (int g = g0; g < g0 + 2; ++g) {
        const int row0 = g * 16;
        const int cell = row0 >> 7;
        const int c = cell & (NCELL - 1);
        const int arow = row0 + lr;
        const int nro = arow & 127;

        bf16x8 aH[2], aG[2];
        #pragma unroll
        for (int ks = 0; ks < 2; ++ks) {
            const float* hr = h + (size_t)arow * 64 + ks * 32 + lg * 8;
            const float* nr = nid + (size_t)(arow & 32767) * 64 + ks * 32 + lg * 8;
            const float* ar = agg_ws + (size_t)arow * 64 + ks * 32 + lg * 8;
            float4 a0 = *(const float4*)hr;
            float4 a1 = *(const float4*)(hr + 4);
            float4 n0 = *(const float4*)nr;
            float4 n1 = *(const float4*)(nr + 4);
            float4 g0v = *(const float4*)ar;
            float4 g1v = *(const float4*)(ar + 4);
            float v[8] = {a0.x, a0.y, a0.z, a0.w, a1.x, a1.y, a1.z, a1.w};
            float nn[8] = {n0.x, n0.y, n0.z, n0.w, n1.x, n1.y, n1.z, n1.w};
            float gg[8] = {g0v.x, g0v.y, g0v.z, g0v.w, g1v.x, g1v.y, g1v.z, g1v.w};
            unsigned short uh[8], ug[8];
            #pragma unroll
            for (int j = 0; j < 8; ++j) {
                float hv = v[j] + nn[j];
                if (nro < 2) hv += inj_ws[cell * 128 + nro * 64 + ks * 32 + lg * 8 + j];
                uh[j] = f2bf(hv);
                ug[j] = f2bf(gg[j]);
            }
            aH[ks] = *(bf16x8*)uh;
            aG[ks] = *(bf16x8*)ug;
        }

        f32x4 accD[4];
        #pragma unroll
        for (int dt = 0; dt < 4; ++dt) accD[dt] = (f32x4){0.f, 0.f, 0.f, 0.f};
        #pragma unroll
        for (int ch = 0; ch < 8; ++ch) {
            f32x4 accS[2];
            accS[0] = (f32x4){0.f, 0.f, 0.f, 0.f};
            accS[1] = (f32x4){0.f, 0.f, 0.f, 0.f};
            #pragma unroll
            for (int ks = 0; ks < 4; ++ks) {
                bf16x8 af = (ks < 2) ? aH[ks] : aG[ks - 2];
                #pragma unroll
                for (int ht = 0; ht < 2; ++ht) {
                    const int wrow = ch * 32 + ht * 16 + lr;
                    bf16x8 bw = *(const bf16x8*)&w1s_s[wrow * 128 + swzg(ks * 32 + lg * 8, wrow)];
                    accS[ht] = MFMA(af, bw, accS[ht]);
                }
            }
            #pragma unroll
            for (int ht = 0; ht < 2; ++ht)
                #pragma unroll
                for (int r = 0; r < 4; ++r)
                    hbuf[swb(lg * 4 + r, ht * 16 + lr)] =
                        f2bf(ftanh(accS[ht][r] + sb1v[ch * 2 + ht]));
            bf16x8 aS = *(const bf16x8*)&hbuf[swb(lr, lg * 8)];
            #pragma unroll
            for (int dt = 0; dt < 4; ++dt) {
                bf16x8 bw = *(const bf16x8*)&w2s_g[(dt * 16 + lr) * 256 + ch * 32 + lg * 8];
                accD[dt] = MFMA(aS, bw, accD[dt]);
            }
        }

        // ---- decay_new, h_new ----
        #pragma unroll
        for (int r = 0; r < 4; ++r) {
            float s = 0.f;
            #pragma unroll
            for (int dt = 0; dt < 4; ++dt) {
                accD[dt][r] += sb2v[dt];
                s += accD[dt][r];
            }
            s += __shfl_xor(s, 1);
            s += __shfl_xor(s, 2);
            s += __shfl_xor(s, 4);
            s += __shfl_xor(s, 8);
            const int row2 = row0 + lg * 4 + r;
            const int nro2 = row2 & 127;
            float mean = s * (1.0f / 64.0f);
            float dg = 0.5f * sigm(dgl[c * 128 + nro2]);
            float dn = (1.0f - dg) * decay[row2] + dg * sigm(mean);
            if (lr == 0) out_d[row2] = dn;
            const float* hrr = h + (size_t)row2 * 64;
            #pragma unroll
            for (int dt = 0; dt < 4; ++dt) {
                int col = dt * 16 + lr;
                float hpost = hrr[col];
                if (nro2 < 2) hpost += inj_ws[cell * 128 + nro2 * 64 + col];
                float hn = (1.0f - dn) * hpost + dn * ftanh(accD[dt][r]);
                out_h[(size_t)row2 * 64 + col] = hn;
            }
        }
    }
}

// ================= hebb: outer + hebbian/W streaming update =================
__global__ __launch_bounds__(256, 4)
void hebb_kernel(const float* __restrict__ W, const float* __restrict__ hebb,
                 const float* __restrict__ wdl, const float* __restrict__ hdl,
                 float* __restrict__ out) {
    const int cell = blockIdx.x;
    const int c = cell & (NCELL - 1);
    const int tid = threadIdx.x;
    const int wv = tid >> 6;
    const int lane = tid & 63;
    const int lr = lane & 15;
    const int lg = lane >> 4;

    const float* hsrc = out + (size_t)cell * 8192;              // h_new
    const float* msrc = out + 16777216 + (size_t)cell * 8192;   // m
    float* out_W  = out + 33554432;
    float* out_hb = out + 67371008;

    __shared__ alignas(16) unsigned char smem[32768];
    unsigned short* hA = (unsigned short*)smem;
    unsigned short* mB = (unsigned short*)(smem + 16384);

    #pragma unroll
    for (int g = 0; g < 8; ++g) {
        int idx = g * 1024 + tid * 4;
        int row = idx >> 6, col = idx & 63;
        float4 hv = *(const float4*)(hsrc + idx);
        float4 mv = *(const float4*)(msrc + idx);
        u16x4 hu = {f2bf(hv.x), f2bf(hv.y), f2bf(hv.z), f2bf(hv.w)};
        u16x4 mu = {f2bf(mv.x), f2bf(mv.y), f2bf(mv.z), f2bf(mv.w)};
        *(u16x4*)&hA[sw64(row, col)] = hu;
        *(u16x4*)&mB[sw64(row, col)] = mu;
    }
    __syncthreads();

    bf16x8 aO[2][2];
    #pragma unroll
    for (int rt = 0; rt < 2; ++rt)
        #pragma unroll
        for (int ks = 0; ks < 2; ++ks)
            aO[rt][ks] = *(const bf16x8*)&hA[sw64(wv * 32 + rt * 16 + lr, ks * 32 + lg * 8)];

    f32x4 accO[2][8];
    #pragma unroll
    for (int rt = 0; rt < 2; ++rt)
        #pragma unroll
        for (int jt = 0; jt < 8; ++jt)
            accO[rt][jt] = (f32x4){0.f, 0.f, 0.f, 0.f};
    #pragma unroll
    for (int jt = 0; jt < 8; ++jt)
        #pragma unroll
        for (int ks = 0; ks < 2; ++ks) {
            bf16x8 bm = *(const bf16x8*)&mB[sw64(jt * 16 + lr, ks * 32 + lg * 8)];
            #pragma unroll
            for (int rt = 0; rt < 2; ++rt)
                accO[rt][jt] = MFMA(aO[rt][ks], bm, accO[rt][jt]);
        }

    #pragma unroll
    for (int rt = 0; rt < 2; ++rt)
        #pragma unroll
        for (int r = 0; r < 4; ++r) {
            int i = wv * 32 + rt * 16 + lg * 4 + r;
            float hg = 0.5f * sigm(hdl[c * 128 + i]);
            float wg = 0.5f * sigm(wdl[c * 128 + i]);
            const float* hbr = hebb + (size_t)(cell * 128 + i) * 128;
            const float* Wr = W + (size_t)(cell * 128 + i) * 128;
            float* ohb = out_hb + (size_t)(cell * 128 + i) * 128;
            float wpre[8];
            float ss = 0.f;
            #pragma unroll
            for (int jt = 0; jt < 8; ++jt) {
                int j = jt * 16 + lr;
                float o = accO[rt][jt][r] * (1.0f / 64.0f);
                float hbn = (1.0f - hg) * hbr[j] + hg * o;
                ohb[j] = hbn;
                float wp = (1.0f - wg) * Wr[j] + wg * hbn;
                wpre[jt] = wp;
                ss += wp * wp;
            }
            ss += __shfl_xor(ss, 1);
            ss += __shfl_xor(ss, 2);
            ss += __shfl_xor(ss, 4);
            ss += __shfl_xor(ss, 8);
            float scale = rsqrtf(ss * (1.0f / 128.0f) + 1e-6f);
            float* oW = out_W + (size_t)(cell * 128 + i) * 128;
            #pragma unroll
            for (int jt = 0; jt < 8; ++jt)
                oW[jt * 16 + lr] = wpre[jt] * scale;
        }
}

extern "C" void kernel_launch(void* const* d_in, const int* in_sizes, int n_in,
                              void* d_out, int out_size, void* d_ws, size_t ws_size,
                              hipStream_t stream) {
    const float* x    = (const float*)d_in[0];
    const float* h    = (const float*)d_in[1];
    const float* W    = (const float*)d_in[2];
    const float* dec  = (const float*)d_in[3];
    const float* hebb = (const float*)d_in[4];
    const float* nid  = (const float*)d_in[5];
    const float* sw1  = (const float*)d_in[6];
    const float* sb1  = (const float*)d_in[7];
    const float* sw2  = (const float*)d_in[8];
    const float* sb2  = (const float*)d_in[9];
    const float* mw1  = (const float*)d_in[10];
    const float* mb1  = (const float*)d_in[11];
    const float* mw2  = (const float*)d_in[12];
    const float* mb2  = (const float*)d_in[13];
    const float* injw = (const float*)d_in[14];
    const float* injb = (const float*)d_in[15];
    const float* wdl  = (const float*)d_in[16];
    const float* dgl  = (const float*)d_in[17];
    const float* hdl  = (const float*)d_in[18];

    float* out = (float*)d_out;
    unsigned short* wbf = (unsigned short*)d_ws;          // 128 KB
    float* out_m  = out + 16777216;
    float* agg_ws = out + 33554432;                       // out_W region (hebb-written last)
    float* out_h  = out;
    float* out_d  = out + 67108864;
    float* inj_ws = out + 67371008;                       // out_hb region start
    unsigned short* mT_g = (unsigned short*)(out + 67371008 + 262144);  // 33.5 MB

    cvt_w<<<256, 256, 0, stream>>>(mw1, mw2, sw1, sw2, wbf);
    inj_kernel<<<4096, 256, 0, stream>>>(x, injw, injb, inj_ws);
    msg_kernel<<<1024, 256, 0, stream>>>(h, nid, mb1, mb2, wbf, inj_ws, out_m, mT_g);
    agg_kernel<<<2048, 256, 0, stream>>>(W, mT_g, agg_ws);
    state_kernel<<<1024, 512, 0, stream>>>(h, nid, dec, sb1, sb2, dgl, wbf,
                                           inj_ws, agg_ws, out_h, out_d);
    hebb_kernel<<<2048, 256, 0, stream>>>(W, hebb, wdl, hdl, out);
}

// Round 10
// 460.164 us; speedup vs baseline: 1.0832x; 1.0832x over previous
//
#include <hip/hip_runtime.h>
#include <hip/hip_bf16.h>

// MemoryGraph: B=8, NC=256, Nc=128, D_n=64, HS=256, HM=128, ALPHA=2
// R10: ZERO-BARRIER cell chain. One wave = one full cell; 512 blocks x 4 waves.
//   Wave-private LDS (mT 16K + hbuf 1K per wave); no __syncthreads in the
//   chain kernel at all; weights bf16 linear from L2; loops rolled for small
//   hot body. inj_kernel precomputes injection; hebb_kernel at HBM roofline.

#define NCELL 256

typedef __attribute__((ext_vector_type(8))) short bf16x8;
typedef __attribute__((ext_vector_type(4))) float f32x4;
typedef __attribute__((ext_vector_type(4))) unsigned short u16x4;

#define MFMA(a, b, c) __builtin_amdgcn_mfma_f32_16x16x32_bf16((a), (b), (c), 0, 0, 0)

__device__ __forceinline__ unsigned short f2bf(float f) {
    return __builtin_bit_cast(unsigned short, __float2bfloat16(f));
}
__device__ __forceinline__ float frcp(float x) { return __builtin_amdgcn_rcpf(x); }
__device__ __forceinline__ float sigm(float v) { return frcp(1.0f + __expf(-v)); }
__device__ __forceinline__ float ftanh(float x) {
    float e = __expf(2.0f * x);
    return 1.0f - 2.0f * frcp(e + 1.0f);
}

// [16][32] per-wave stage swizzle (4 granules)
__device__ __forceinline__ int swb(int row, int col) {
    return row * 32 + ((((col >> 3) ^ row) & 3) << 3) + (col & 7);
}
// [64][128] per-wave mT swizzle (16 granules, XOR low 3 bits by row)
__device__ __forceinline__ int swm(int d, int col) {
    return d * 128 + ((((col >> 3) ^ (d & 7)) & 15) << 3) + (col & 7);
}
__device__ __forceinline__ int sw64(int row, int col) {
    return row * 64 + ((((col >> 3) ^ row) & 7) << 3) + (col & 7);
}

// ws layout (ushort, all LINEAR row-major):
// [0,8192) w1m [128][64]; [8192,16384) w2m [64][128];
// [16384,49152) w1s [256][128]; [49152,65536) w2s [64][256].
__global__ void cvt_w(const float* __restrict__ a, const float* __restrict__ b,
                      const float* __restrict__ c, const float* __restrict__ d,
                      unsigned short* __restrict__ dst) {
    int i = blockIdx.x * 256 + threadIdx.x;   // 65536 total
    float v;
    if (i < 8192) v = a[i];
    else if (i < 16384) v = b[i - 8192];
    else if (i < 49152) v = c[i - 16384];
    else v = d[i - 49152];
    dst[i] = f2bf(v);
}

// ================= inj = x @ injw^T + injb =================
__global__ __launch_bounds__(256, 8)
void inj_kernel(const float* __restrict__ x, const float* __restrict__ injw,
                const float* __restrict__ injb, float* __restrict__ inj_ws) {
    int t = blockIdx.x * 256 + threadIdx.x;   // 1048576 = 262144 outputs x 4
    int oid = t >> 2;
    int part = t & 3;
    int cell = oid >> 7, o = oid & 127, c = cell & (NCELL - 1);
    const float4* wr = (const float4*)(injw + (c * 128 + o) * 64 + part * 16);
    const float4* xr = (const float4*)(x + cell * 64 + part * 16);
    float s = 0.f;
    #pragma unroll
    for (int i = 0; i < 4; ++i) {
        float4 a = wr[i], b = xr[i];
        s += a.x * b.x + a.y * b.y + a.z * b.z + a.w * b.w;
    }
    s += __shfl_xor(s, 1);
    s += __shfl_xor(s, 2);
    if (part == 0) inj_ws[oid] = s + injb[c * 128 + o];
}

// ================= K1: zero-barrier, one wave per cell =================
__global__ __launch_bounds__(256, 2)
void cell_wave_kernel(const float* __restrict__ h, const float* __restrict__ W,
                      const float* __restrict__ decay, const float* __restrict__ nid,
                      const float* __restrict__ sb1, const float* __restrict__ sb2,
                      const float* __restrict__ mb1, const float* __restrict__ mb2,
                      const float* __restrict__ dgl,
                      const unsigned short* __restrict__ wbf,
                      const float* __restrict__ inj_ws,
                      float* __restrict__ out_h, float* __restrict__ out_m,
                      float* __restrict__ out_d) {
    const int tid = threadIdx.x;
    const int wv = tid >> 6;
    const int lane = tid & 63;
    const int lr = lane & 15;
    const int lg = lane >> 4;
    const int cell = blockIdx.x * 4 + wv;
    const int c = cell & (NCELL - 1);

    const unsigned short* w1m = wbf;              // [128][64]
    const unsigned short* w2m = wbf + 8192;       // [64][128]
    const unsigned short* w1s = wbf + 16384;      // [256][128]
    const unsigned short* w2s = wbf + 49152;      // [64][256]

    __shared__ alignas(16) unsigned short mT_all[4][8192];   // 64 KB
    __shared__ alignas(16) unsigned short hbuf_all[4][512];  // 4 KB
    unsigned short* mT = mT_all[wv];
    unsigned short* hbuf = hbuf_all[wv];

    const float* hc = h + (size_t)cell * 8192;
    const float* nc = nid + (size_t)c * 8192;
    const float* injc = inj_ws + (size_t)cell * 128;

    // ================= Phase A: m = tanh(h_id@w1m^T+b1)@w2m^T+b2 =================
    #pragma unroll 1
    for (int rt = 0; rt < 8; ++rt) {
        const int row = rt * 16 + lr;
        bf16x8 aH[2];
        #pragma unroll
        for (int ks = 0; ks < 2; ++ks) {
            const int col = ks * 32 + lg * 8;
            float4 a0 = *(const float4*)(hc + row * 64 + col);
            float4 a1 = *(const float4*)(hc + row * 64 + col + 4);
            float4 n0 = *(const float4*)(nc + row * 64 + col);
            float4 n1 = *(const float4*)(nc + row * 64 + col + 4);
            float v[8] = {a0.x, a0.y, a0.z, a0.w, a1.x, a1.y, a1.z, a1.w};
            float nn[8] = {n0.x, n0.y, n0.z, n0.w, n1.x, n1.y, n1.z, n1.w};
            unsigned short us[8];
            #pragma unroll
            for (int j = 0; j < 8; ++j) {
                float hv = v[j] + nn[j];
                if (row < 2) hv += injc[row * 64 + col + j];
                us[j] = f2bf(hv);
            }
            aH[ks] = *(bf16x8*)us;
        }

        f32x4 accM[4];
        #pragma unroll
        for (int dt = 0; dt < 4; ++dt) accM[dt] = (f32x4){0.f, 0.f, 0.f, 0.f};

        #pragma unroll 1
        for (int ch = 0; ch < 4; ++ch) {
            f32x4 accH[2];
            accH[0] = (f32x4){0.f, 0.f, 0.f, 0.f};
            accH[1] = (f32x4){0.f, 0.f, 0.f, 0.f};
            #pragma unroll
            for (int ks = 0; ks < 2; ++ks)
                #pragma unroll
                for (int ht = 0; ht < 2; ++ht) {
                    bf16x8 bw = *(const bf16x8*)&w1m[(ch * 32 + ht * 16 + lr) * 64 + ks * 32 + lg * 8];
                    accH[ht] = MFMA(aH[ks], bw, accH[ht]);
                }
            #pragma unroll
            for (int ht = 0; ht < 2; ++ht) {
                float b1v = mb1[ch * 32 + ht * 16 + lr];
                #pragma unroll
                for (int r = 0; r < 4; ++r)
                    hbuf[swb(lg * 4 + r, ht * 16 + lr)] = f2bf(ftanh(accH[ht][r] + b1v));
            }
            bf16x8 aM = *(const bf16x8*)&hbuf[swb(lr, lg * 8)];
            #pragma unroll
            for (int dt = 0; dt < 4; ++dt) {
                bf16x8 bw = *(const bf16x8*)&w2m[(dt * 16 + lr) * 128 + ch * 32 + lg * 8];
                accM[dt] = MFMA(aM, bw, accM[dt]);
            }
        }

        // epilogue: m f32 out + mT bf16 (wave-private LDS)
        const int n0c = rt * 16 + lg * 4;
        #pragma unroll
        for (int dt = 0; dt < 4; ++dt) {
            float b2v = mb2[dt * 16 + lr];
            unsigned short um[4];
            #pragma unroll
            for (int r = 0; r < 4; ++r) {
                float mv = accM[dt][r] + b2v;
                out_m[(size_t)cell * 8192 + (n0c + r) * 64 + dt * 16 + lr] = mv;
                um[r] = f2bf(mv);
            }
            *(u16x4*)&mT[swm(dt * 16 + lr, n0c)] = *(u16x4*)um;
        }
    }

    // ============ Phase B: agg = W@m ; dh = state MLP ; h_new/decay ============
    #pragma unroll 1
    for (int rt = 0; rt < 8; ++rt) {
        const int row = rt * 16 + lr;

        // ---- agg ----
        f32x4 accA[4];
        #pragma unroll
        for (int dt = 0; dt < 4; ++dt) accA[dt] = (f32x4){0.f, 0.f, 0.f, 0.f};
        #pragma unroll
        for (int ks = 0; ks < 4; ++ks) {
            const float* wr = W + (size_t)cell * 16384 + row * 128 + ks * 32 + lg * 8;
            float4 wa = *(const float4*)wr;
            float4 wb = *(const float4*)(wr + 4);
            unsigned short uw[8] = {f2bf(wa.x), f2bf(wa.y), f2bf(wa.z), f2bf(wa.w),
                                    f2bf(wb.x), f2bf(wb.y), f2bf(wb.z), f2bf(wb.w)};
            bf16x8 aW = *(bf16x8*)uw;
            #pragma unroll
            for (int dt = 0; dt < 4; ++dt) {
                bf16x8 bm = *(const bf16x8*)&mT[swm(dt * 16 + lr, ks * 32 + lg * 8)];
                accA[dt] = MFMA(aW, bm, accA[dt]);
            }
        }
        // C->A relayout via wave-private hbuf
        bf16x8 aG[2];
        #pragma unroll
        for (int p = 0; p < 2; ++p) {
            #pragma unroll
            for (int q = 0; q < 2; ++q)
                #pragma unroll
                for (int r = 0; r < 4; ++r)
                    hbuf[swb(lg * 4 + r, q * 16 + lr)] = f2bf(accA[p * 2 + q][r]);
            aG[p] = *(const bf16x8*)&hbuf[swb(lr, lg * 8)];
        }

        // ---- aH rebuild (h/nid/inj from L2) ----
        bf16x8 aH[2];
        #pragma unroll
        for (int ks = 0; ks < 2; ++ks) {
            const int col = ks * 32 + lg * 8;
            float4 a0 = *(const float4*)(hc + row * 64 + col);
            float4 a1 = *(const float4*)(hc + row * 64 + col + 4);
            float4 n0 = *(const float4*)(nc + row * 64 + col);
            float4 n1 = *(const float4*)(nc + row * 64 + col + 4);
            float v[8] = {a0.x, a0.y, a0.z, a0.w, a1.x, a1.y, a1.z, a1.w};
            float nn[8] = {n0.x, n0.y, n0.z, n0.w, n1.x, n1.y, n1.z, n1.w};
            unsigned short us[8];
            #pragma unroll
            for (int j = 0; j < 8; ++j) {
                float hv = v[j] + nn[j];
                if (row < 2) hv += injc[row * 64 + col + j];
                us[j] = f2bf(hv);
            }
            aH[ks] = *(bf16x8*)us;
        }

        // ---- state MLP ----
        f32x4 accD[4];
        #pragma unroll
        for (int dt = 0; dt < 4; ++dt) accD[dt] = (f32x4){0.f, 0.f, 0.f, 0.f};
        #pragma unroll 1
        for (int ch = 0; ch < 8; ++ch) {
            f32x4 accS[2];
            accS[0] = (f32x4){0.f, 0.f, 0.f, 0.f};
            accS[1] = (f32x4){0.f, 0.f, 0.f, 0.f};
            #pragma unroll
            for (int ks = 0; ks < 4; ++ks) {
                bf16x8 af = (ks < 2) ? aH[ks] : aG[ks - 2];
                #pragma unroll
                for (int ht = 0; ht < 2; ++ht) {
                    bf16x8 bw = *(const bf16x8*)&w1s[(ch * 32 + ht * 16 + lr) * 128 + ks * 32 + lg * 8];
                    accS[ht] = MFMA(af, bw, accS[ht]);
                }
            }
            #pragma unroll
            for (int ht = 0; ht < 2; ++ht) {
                float bv = sb1[ch * 32 + ht * 16 + lr];
                #pragma unroll
                for (int r = 0; r < 4; ++r)
                    hbuf[swb(lg * 4 + r, ht * 16 + lr)] = f2bf(ftanh(accS[ht][r] + bv));
            }
            bf16x8 aS = *(const bf16x8*)&hbuf[swb(lr, lg * 8)];
            #pragma unroll
            for (int dt = 0; dt < 4; ++dt) {
                bf16x8 bw = *(const bf16x8*)&w2s[(dt * 16 + lr) * 256 + ch * 32 + lg * 8];
                accD[dt] = MFMA(aS, bw, accD[dt]);
            }
        }

        // ---- decay_new, h_new ----
        #pragma unroll
        for (int r = 0; r < 4; ++r) {
            float s = 0.f;
            #pragma unroll
            for (int dt = 0; dt < 4; ++dt) {
                accD[dt][r] += sb2[dt * 16 + lr];
                s += accD[dt][r];
            }
            s += __shfl_xor(s, 1);
            s += __shfl_xor(s, 2);
            s += __shfl_xor(s, 4);
            s += __shfl_xor(s, 8);
            const int row2 = rt * 16 + lg * 4 + r;
            float mean = s * (1.0f / 64.0f);
            float dg = 0.5f * sigm(dgl[c * 128 + row2]);
            float dn = (1.0f - dg) * decay[(size_t)cell * 128 + row2] + dg * sigm(mean);
            if (lr == 0) out_d[(size_t)cell * 128 + row2] = dn;
            #pragma unroll
            for (int dt = 0; dt < 4; ++dt) {
                int col = dt * 16 + lr;
                float hpost = hc[row2 * 64 + col];
                if (row2 < 2) hpost += injc[row2 * 64 + col];
                float hn = (1.0f - dn) * hpost + dn * ftanh(accD[dt][r]);
                out_h[(size_t)cell * 8192 + row2 * 64 + col] = hn;
            }
        }
    }
}

// ================= hebb: outer + hebbian/W streaming update =================
__global__ __launch_bounds__(256, 4)
void hebb_kernel(const float* __restrict__ W, const float* __restrict__ hebb,
                 const float* __restrict__ wdl, const float* __restrict__ hdl,
                 float* __restrict__ out) {
    const int cell = blockIdx.x;
    const int c = cell & (NCELL - 1);
    const int tid = threadIdx.x;
    const int wv = tid >> 6;
    const int lane = tid & 63;
    const int lr = lane & 15;
    const int lg = lane >> 4;

    const float* hsrc = out + (size_t)cell * 8192;              // h_new
    const float* msrc = out + 16777216 + (size_t)cell * 8192;   // m
    float* out_W  = out + 33554432;
    float* out_hb = out + 67371008;

    __shared__ alignas(16) unsigned char smem[32768];
    unsigned short* hA = (unsigned short*)smem;
    unsigned short* mB = (unsigned short*)(smem + 16384);

    #pragma unroll
    for (int g = 0; g < 8; ++g) {
        int idx = g * 1024 + tid * 4;
        int row = idx >> 6, col = idx & 63;
        float4 hv = *(const float4*)(hsrc + idx);
        float4 mv = *(const float4*)(msrc + idx);
        u16x4 hu = {f2bf(hv.x), f2bf(hv.y), f2bf(hv.z), f2bf(hv.w)};
        u16x4 mu = {f2bf(mv.x), f2bf(mv.y), f2bf(mv.z), f2bf(mv.w)};
        *(u16x4*)&hA[sw64(row, col)] = hu;
        *(u16x4*)&mB[sw64(row, col)] = mu;
    }
    __syncthreads();

    bf16x8 aO[2][2];
    #pragma unroll
    for (int rt = 0; rt < 2; ++rt)
        #pragma unroll
        for (int ks = 0; ks < 2; ++ks)
            aO[rt][ks] = *(const bf16x8*)&hA[sw64(wv * 32 + rt * 16 + lr, ks * 32 + lg * 8)];

    f32x4 accO[2][8];
    #pragma unroll
    for (int rt = 0; rt < 2; ++rt)
        #pragma unroll
        for (int jt = 0; jt < 8; ++jt)
            accO[rt][jt] = (f32x4){0.f, 0.f, 0.f, 0.f};
    #pragma unroll
    for (int jt = 0; jt < 8; ++jt)
        #pragma unroll
        for (int ks = 0; ks < 2; ++ks) {
            bf16x8 bm = *(const bf16x8*)&mB[sw64(jt * 16 + lr, ks * 32 + lg * 8)];
            #pragma unroll
            for (int rt = 0; rt < 2; ++rt)
                accO[rt][jt] = MFMA(aO[rt][ks], bm, accO[rt][jt]);
        }

    #pragma unroll
    for (int rt = 0; rt < 2; ++rt)
        #pragma unroll
        for (int r = 0; r < 4; ++r) {
            int i = wv * 32 + rt * 16 + lg * 4 + r;
            float hg = 0.5f * sigm(hdl[c * 128 + i]);
            float wg = 0.5f * sigm(wdl[c * 128 + i]);
            const float* hbr = hebb + (size_t)(cell * 128 + i) * 128;
            const float* Wr = W + (size_t)(cell * 128 + i) * 128;
            float* ohb = out_hb + (size_t)(cell * 128 + i) * 128;
            float wpre[8];
            float ss = 0.f;
            #pragma unroll
            for (int jt = 0; jt < 8; ++jt) {
                int j = jt * 16 + lr;
                float o = accO[rt][jt][r] * (1.0f / 64.0f);
                float hbn = (1.0f - hg) * hbr[j] + hg * o;
                ohb[j] = hbn;
                float wp = (1.0f - wg) * Wr[j] + wg * hbn;
                wpre[jt] = wp;
                ss += wp * wp;
            }
            ss += __shfl_xor(ss, 1);
            ss += __shfl_xor(ss, 2);
            ss += __shfl_xor(ss, 4);
            ss += __shfl_xor(ss, 8);
            float scale = rsqrtf(ss * (1.0f / 128.0f) + 1e-6f);
            float* oW = out_W + (size_t)(cell * 128 + i) * 128;
            #pragma unroll
            for (int jt = 0; jt < 8; ++jt)
                oW[jt * 16 + lr] = wpre[jt] * scale;
        }
}

extern "C" void kernel_launch(void* const* d_in, const int* in_sizes, int n_in,
                              void* d_out, int out_size, void* d_ws, size_t ws_size,
                              hipStream_t stream) {
    const float* x    = (const float*)d_in[0];
    const float* h    = (const float*)d_in[1];
    const float* W    = (const float*)d_in[2];
    const float* dec  = (const float*)d_in[3];
    const float* hebb = (const float*)d_in[4];
    const float* nid  = (const float*)d_in[5];
    const float* sw1  = (const float*)d_in[6];
    const float* sb1  = (const float*)d_in[7];
    const float* sw2  = (const float*)d_in[8];
    const float* sb2  = (const float*)d_in[9];
    const float* mw1  = (const float*)d_in[10];
    const float* mb1  = (const float*)d_in[11];
    const float* mw2  = (const float*)d_in[12];
    const float* mb2  = (const float*)d_in[13];
    const float* injw = (const float*)d_in[14];
    const float* injb = (const float*)d_in[15];
    const float* wdl  = (const float*)d_in[16];
    const float* dgl  = (const float*)d_in[17];
    const float* hdl  = (const float*)d_in[18];

    float* out = (float*)d_out;
    unsigned short* wbf = (unsigned short*)d_ws;   // 128 KB
    float* out_h  = out;
    float* out_m  = out + 16777216;
    float* out_d  = out + 67108864;
    float* inj_ws = out + 67371008;                // out_hb region (hebb writes last)

    cvt_w<<<256, 256, 0, stream>>>(mw1, mw2, sw1, sw2, wbf);
    inj_kernel<<<4096, 256, 0, stream>>>(x, injw, injb, inj_ws);
    cell_wave_kernel<<<512, 256, 0, stream>>>(h, W, dec, nid, sb1, sb2, mb1, mb2,
                                              dgl, wbf, inj_ws, out_h, out_m, out_d);
    hebb_kernel<<<2048, 256, 0, stream>>>(W, hebb, wdl, hdl, out);
}